// Round 9
// baseline (424.531 us; speedup 1.0000x reference)
//
#include <hip/hip_runtime.h>
#include <math.h>

#define B_     256
#define S_     500
#define QD_    128
#define M_     64
#define VD_    256
#define CH_    16
#define NQ_    10000          // q indices in [0, 10000]
#define NQA_   20000          // qa indices in [0, 20000]
#define WROWS  (NQ_ + 1)
#define EAROWS (NQA_ + 1)

typedef unsigned int u32;
typedef float f16v __attribute__((ext_vector_type(16)));

// global -> LDS async copy, 16B per lane. LDS dest must be wave-uniform
// base + lane*16.
__device__ __forceinline__ void gload_lds16(const float* g, float* l)
{
    __builtin_amdgcn_global_load_lds(
        (const __attribute__((address_space(1))) u32*)(const void*)g,
        (__attribute__((address_space(3))) u32*)(void*)l, 16, 0, 0);
}

// ---------------------------------------------------------------------------
// Transpose key_mem [64][128] into quad layout kTq[k4*64 + m].
// ---------------------------------------------------------------------------
__global__ void kT_kernel(const float* __restrict__ key_mem, float4* __restrict__ kTq)
{
    int i = blockIdx.x * 256 + threadIdx.x;
    if (i < 32 * 64) {
        int m  = i & 63;
        int k4 = i >> 6;
        kTq[i] = *reinterpret_cast<const float4*>(&key_mem[m * QD_ + k4 * 4]);
    }
}

// ---------------------------------------------------------------------------
// wtab[r][m] = softmax_m( q_embed_w[r] . key_mem[m] ),  r in [0, WROWS)
// ---------------------------------------------------------------------------
__global__ __launch_bounds__(256) void wtab_kernel(
    const float*  __restrict__ q_embed_w,
    const float4* __restrict__ kTq,
    float*        __restrict__ wtab)
{
    __shared__ float4 q4[16][32];

    const int tid = threadIdx.x;
    const int r0  = blockIdx.x * 16;

    for (int i = tid; i < 512; i += 256) {
        int row = i >> 5, k4 = i & 31;
        int r   = r0 + row; if (r > NQ_) r = NQ_;
        q4[row][k4] = *reinterpret_cast<const float4*>(
            &q_embed_w[(size_t)r * QD_ + k4 * 4]);
    }
    __syncthreads();

    const int wave = tid >> 6, lane = tid & 63;
    const int rr = wave * 4;

    float s0 = 0.f, s1 = 0.f, s2 = 0.f, s3 = 0.f;
    for (int k4 = 0; k4 < 32; ++k4) {
        float4 kv = kTq[k4 * 64 + lane];
        float4 a0 = q4[rr + 0][k4];
        float4 a1 = q4[rr + 1][k4];
        float4 a2 = q4[rr + 2][k4];
        float4 a3 = q4[rr + 3][k4];
        s0 = fmaf(a0.x, kv.x, s0); s0 = fmaf(a0.y, kv.y, s0);
        s0 = fmaf(a0.z, kv.z, s0); s0 = fmaf(a0.w, kv.w, s0);
        s1 = fmaf(a1.x, kv.x, s1); s1 = fmaf(a1.y, kv.y, s1);
        s1 = fmaf(a1.z, kv.z, s1); s1 = fmaf(a1.w, kv.w, s1);
        s2 = fmaf(a2.x, kv.x, s2); s2 = fmaf(a2.y, kv.y, s2);
        s2 = fmaf(a2.z, kv.z, s2); s2 = fmaf(a2.w, kv.w, s2);
        s3 = fmaf(a3.x, kv.x, s3); s3 = fmaf(a3.y, kv.y, s3);
        s3 = fmaf(a3.z, kv.z, s3); s3 = fmaf(a3.w, kv.w, s3);
    }

    float s[4] = { s0, s1, s2, s3 };
    #pragma unroll
    for (int j = 0; j < 4; ++j) {
        float mx = s[j];
        #pragma unroll
        for (int off = 32; off; off >>= 1) mx = fmaxf(mx, __shfl_xor(mx, off));
        float e = __expf(s[j] - mx);
        float sum = e;
        #pragma unroll
        for (int off = 32; off; off >>= 1) sum += __shfl_xor(sum, off);
        if (r0 + rr + j < WROWS)
            wtab[(size_t)(r0 + rr + j) * 64 + lane] = e / sum;
    }
}

// ---------------------------------------------------------------------------
// eatab[r][0..255]   = sigmoid(qa_embed_w[r] @ erase_W + erase_b)
// eatab[r][256..511] = tanh   (qa_embed_w[r] @ add_W   + add_b)
// ---------------------------------------------------------------------------
__global__ __launch_bounds__(512) void eatab_kernel(
    const float* __restrict__ qa_embed_w,
    const float* __restrict__ erase_W,
    const float* __restrict__ erase_b,
    const float* __restrict__ add_W,
    const float* __restrict__ add_b,
    float*       __restrict__ eatab)
{
    __shared__ float4 qa4[16][32];

    const int tid = threadIdx.x;
    const int r0  = blockIdx.x * 16;

    {
        int row = tid >> 5, k4 = tid & 31;
        int r   = r0 + row; if (r > NQA_) r = NQA_;
        qa4[row][k4] = *reinterpret_cast<const float4*>(
            &qa_embed_w[(size_t)r * QD_ + k4 * 4]);
    }
    __syncthreads();

    const int  c   = tid & 255;
    const bool isE = tid < 256;
    const float* Wp = isE ? erase_W : add_W;

    float acc[16];
    #pragma unroll
    for (int r = 0; r < 16; ++r) acc[r] = 0.f;

    for (int k4 = 0; k4 < 32; ++k4) {
        float w0 = Wp[(size_t)(k4 * 4 + 0) * 256 + c];
        float w1 = Wp[(size_t)(k4 * 4 + 1) * 256 + c];
        float w2 = Wp[(size_t)(k4 * 4 + 2) * 256 + c];
        float w3 = Wp[(size_t)(k4 * 4 + 3) * 256 + c];
        #pragma unroll
        for (int r = 0; r < 16; ++r) {
            float4 qv = qa4[r][k4];
            acc[r] = fmaf(qv.x, w0, acc[r]);
            acc[r] = fmaf(qv.y, w1, acc[r]);
            acc[r] = fmaf(qv.z, w2, acc[r]);
            acc[r] = fmaf(qv.w, w3, acc[r]);
        }
    }

    const float bias = isE ? erase_b[c] : add_b[c];
    #pragma unroll
    for (int r = 0; r < 16; ++r) {
        float x = acc[r] + bias;
        float y;
        if (isE) {
            y = 1.f / (1.f + __expf(-x));
        } else {
            float t  = __expf(-2.f * fabsf(x));
            float ta = (1.f - t) / (1.f + t);
            y = (x < 0.f) ? -ta : ta;
        }
        if (r0 + r < EAROWS)
            eatab[(size_t)(r0 + r) * 512 + tid] = y;
    }
}

// ---------------------------------------------------------------------------
// e/a staging: one CH_-step chunk gathered global->LDS via global_load_lds.
//   ebuf/abuf[st*256 + col]
// ---------------------------------------------------------------------------
__device__ __forceinline__ void stage_ea(
    int tb, int tid, const int* __restrict__ qarow,
    const float* __restrict__ eatab, float* ebuf, float* abuf)
{
    #pragma unroll
    for (int j = 0; j < 4; ++j) {
        const int idx = tid + 256 * j;          // quad index 0..1023
        int st = tb + (idx >> 6); if (st >= S_) st = S_ - 1;
        const int cq = (idx & 63) * 4;
        const float* rowp = &eatab[(size_t)qarow[st] * 512];
        gload_lds16(&rowp[cq],       &ebuf[(idx & ~63) * 4]);
        gload_lds16(&rowp[256 + cq], &abuf[(idx & ~63) * 4]);
    }
}

// ---------------------------------------------------------------------------
// Scan: 256 blocks (1/batch) x 256 threads (4 waves).
// Thread tid owns the FULL Mv column col=tid: mv[64] in VGPRs.
// w is WAVE-UNIFORM -> lives in SGPRs via s_load_dwordx16 (4x f16v),
// single-buffered, prefetched one step ahead (q-index chain 3 ahead,
// readfirstlane-forced uniform). No w LDS traffic, no cross-lane
// reduction, unguarded coalesced b32 stores.
// e/a staged global->LDS per chunk (double-buffered) as before.
// ---------------------------------------------------------------------------
__global__ __launch_bounds__(256, 1) void scan_kernel(
    const int*   __restrict__ q_data,
    const int*   __restrict__ qa_data,
    const float* __restrict__ init_mv,
    const float* __restrict__ wtab,
    const float* __restrict__ eatab,
    float*       __restrict__ out)
{
    __shared__ float e_lds[2][CH_ * VD_];    // 32 KB
    __shared__ float a_lds[2][CH_ * VD_];    // 32 KB
    __shared__ int   qarow[S_];

    const int b   = blockIdx.x;
    const int tid = threadIdx.x;

    for (int i = tid; i < S_; i += 256) qarow[i] = qa_data[b * S_ + i];
    __syncthreads();                     // qarow ready for staging

    stage_ea(0, tid, qarow, eatab, e_lds[0], a_lds[0]);

    // full column state
    float mv[64];
    #pragma unroll
    for (int m = 0; m < 64; ++m) mv[m] = init_mv[m * VD_ + tid];
    out[(size_t)b * S_ * VD_ + tid] = 0.f;

    // uniform q-index chain: qc = q[t], q1 = q[t+1], q2 = q[t+2]
    const int* __restrict__ qp = q_data + (size_t)b * S_;
    int qc = __builtin_amdgcn_readfirstlane(qp[0]);
    int q1 = __builtin_amdgcn_readfirstlane(qp[1]);
    int q2 = __builtin_amdgcn_readfirstlane(qp[2]);

    // w for step 0 (uniform row -> SMEM)
    const f16v* wr0 = (const f16v*)(wtab + (size_t)qc * 64);
    f16v wA = wr0[0], wB = wr0[1], wC = wr0[2], wD = wr0[3];

    __syncthreads();                     // chunk 0 staged (vmcnt drained)

    const int nch = (S_ + CH_ - 1) / CH_;
    for (int c = 0; c < nch; ++c) {
        const int  tb  = c * CH_;
        const int  buf = c & 1;
        const bool hn  = (c + 1 < nch);

        if (hn)
            stage_ea(tb + CH_, tid, qarow, eatab, e_lds[buf ^ 1], a_lds[buf ^ 1]);

        const float* eb = &e_lds[buf][tid];
        const float* ab = &a_lds[buf][tid];
        float* outp = &out[((size_t)b * S_ + tb + 1) * VD_ + tid];

        #pragma unroll
        for (int tt = 0; tt < CH_; ++tt) {
            const int t = tb + tt;
            if (t < S_) {
                const float ev = eb[tt * VD_];
                const float av = ab[tt * VD_];
                const bool  wr = qc >= 1;
                const float em = wr ? ev : 0.f;
                const float am = wr ? av : 0.f;

                float r0 = 0.f, r1 = 0.f, r2 = 0.f, r3 = 0.f;
                #pragma unroll
                for (int k = 0; k < 16; ++k) {
                    const float w0 = wA[k], w1 = wB[k], w2 = wC[k], w3 = wD[k];
                    const float v0 = mv[k], v1 = mv[16 + k];
                    const float v2 = mv[32 + k], v3 = mv[48 + k];
                    r0 = fmaf(w0, v0, r0);
                    r1 = fmaf(w1, v1, r1);
                    r2 = fmaf(w2, v2, r2);
                    r3 = fmaf(w3, v3, r3);
                    mv[k]      = fmaf(w0, fmaf(-em, v0, am), v0);
                    mv[16 + k] = fmaf(w1, fmaf(-em, v1, am), v1);
                    mv[32 + k] = fmaf(w2, fmaf(-em, v2, am), v2);
                    mv[48 + k] = fmaf(w3, fmaf(-em, v3, am), v3);
                }
                const float rd = (r0 + r1) + (r2 + r3);

                if (t + 1 < S_) {
                    outp[(size_t)tt * VD_] = rd;
                    // rotate: prefetch w for step t+1, q-index for t+3
                    const f16v* wn = (const f16v*)(wtab + (size_t)q1 * 64);
                    wA = wn[0]; wB = wn[1]; wC = wn[2]; wD = wn[3];
                    qc = q1;
                    q1 = q2;
                    int t3 = t + 3; if (t3 >= S_) t3 = S_ - 1;
                    q2 = __builtin_amdgcn_readfirstlane(qp[t3]);
                }
            }
        }
        __syncthreads();   // next chunk staged + everyone done with buf
    }
}

// ---------------------------------------------------------------------------
extern "C" void kernel_launch(void* const* d_in, const int* in_sizes, int n_in,
                              void* d_out, int out_size, void* d_ws, size_t ws_size,
                              hipStream_t stream)
{
    const int*   q_data  = (const int*)  d_in[0];
    const int*   qa_data = (const int*)  d_in[1];
    const float* q_emb   = (const float*)d_in[2];
    const float* qa_emb  = (const float*)d_in[3];
    const float* key_mem = (const float*)d_in[4];
    const float* init_mv = (const float*)d_in[5];
    const float* erase_W = (const float*)d_in[6];
    const float* erase_b = (const float*)d_in[7];
    const float* add_W   = (const float*)d_in[8];
    const float* add_b   = (const float*)d_in[9];
    float* out = (float*)d_out;

    char* ws = (char*)d_ws;
    float4* kTq = (float4*)ws;
    size_t off = (size_t)2048 * sizeof(float4);               // 32 KB
    float* wtab = (float*)(ws + off);
    off += (size_t)WROWS * 64 * sizeof(float);                // 2.56 MB
    off = (off + 255) & ~(size_t)255;
    float* eatab = (float*)(ws + off);
    off += (size_t)EAROWS * 512 * sizeof(float);              // 40.96 MB

    kT_kernel<<<dim3(8), dim3(256), 0, stream>>>(key_mem, kTq);
    wtab_kernel<<<dim3((WROWS + 15) / 16), dim3(256), 0, stream>>>(
        q_emb, kTq, wtab);
    eatab_kernel<<<dim3((EAROWS + 15) / 16), dim3(512), 0, stream>>>(
        qa_emb, erase_W, erase_b, add_W, add_b, eatab);
    scan_kernel<<<dim3(B_), dim3(256), 0, stream>>>(
        q_data, qa_data, init_mv, wtab, eatab, out);
}

// Round 10
// 386.538 us; speedup vs baseline: 1.0983x; 1.0983x over previous
//
#include <hip/hip_runtime.h>
#include <math.h>

#define B_     256
#define S_     500
#define QD_    128
#define M_     64
#define VD_    256
#define NQ_    10000          // q indices in [0, 10000]
#define NQA_   20000          // qa indices in [0, 20000]
#define WROWS  (NQ_ + 1)
#define EAROWS (NQA_ + 1)

// ---------------------------------------------------------------------------
// Transpose key_mem [64][128] into quad layout kTq[k4*64 + m].
// ---------------------------------------------------------------------------
__global__ void kT_kernel(const float* __restrict__ key_mem, float4* __restrict__ kTq)
{
    int i = blockIdx.x * 256 + threadIdx.x;
    if (i < 32 * 64) {
        int m  = i & 63;
        int k4 = i >> 6;
        kTq[i] = *reinterpret_cast<const float4*>(&key_mem[m * QD_ + k4 * 4]);
    }
}

// ---------------------------------------------------------------------------
// wtab[r][m] = softmax_m( q_embed_w[r] . key_mem[m] ),  r in [0, WROWS)
// ---------------------------------------------------------------------------
__global__ __launch_bounds__(256) void wtab_kernel(
    const float*  __restrict__ q_embed_w,
    const float4* __restrict__ kTq,
    float*        __restrict__ wtab)
{
    __shared__ float4 q4[16][32];

    const int tid = threadIdx.x;
    const int r0  = blockIdx.x * 16;

    for (int i = tid; i < 512; i += 256) {
        int row = i >> 5, k4 = i & 31;
        int r   = r0 + row; if (r > NQ_) r = NQ_;
        q4[row][k4] = *reinterpret_cast<const float4*>(
            &q_embed_w[(size_t)r * QD_ + k4 * 4]);
    }
    __syncthreads();

    const int wave = tid >> 6, lane = tid & 63;
    const int rr = wave * 4;

    float s0 = 0.f, s1 = 0.f, s2 = 0.f, s3 = 0.f;
    for (int k4 = 0; k4 < 32; ++k4) {
        float4 kv = kTq[k4 * 64 + lane];
        float4 a0 = q4[rr + 0][k4];
        float4 a1 = q4[rr + 1][k4];
        float4 a2 = q4[rr + 2][k4];
        float4 a3 = q4[rr + 3][k4];
        s0 = fmaf(a0.x, kv.x, s0); s0 = fmaf(a0.y, kv.y, s0);
        s0 = fmaf(a0.z, kv.z, s0); s0 = fmaf(a0.w, kv.w, s0);
        s1 = fmaf(a1.x, kv.x, s1); s1 = fmaf(a1.y, kv.y, s1);
        s1 = fmaf(a1.z, kv.z, s1); s1 = fmaf(a1.w, kv.w, s1);
        s2 = fmaf(a2.x, kv.x, s2); s2 = fmaf(a2.y, kv.y, s2);
        s2 = fmaf(a2.z, kv.z, s2); s2 = fmaf(a2.w, kv.w, s2);
        s3 = fmaf(a3.x, kv.x, s3); s3 = fmaf(a3.y, kv.y, s3);
        s3 = fmaf(a3.z, kv.z, s3); s3 = fmaf(a3.w, kv.w, s3);
    }

    float s[4] = { s0, s1, s2, s3 };
    #pragma unroll
    for (int j = 0; j < 4; ++j) {
        float mx = s[j];
        #pragma unroll
        for (int off = 32; off; off >>= 1) mx = fmaxf(mx, __shfl_xor(mx, off));
        float e = __expf(s[j] - mx);
        float sum = e;
        #pragma unroll
        for (int off = 32; off; off >>= 1) sum += __shfl_xor(sum, off);
        if (r0 + rr + j < WROWS)
            wtab[(size_t)(r0 + rr + j) * 64 + lane] = e / sum;
    }
}

// ---------------------------------------------------------------------------
// eatab[r][0..255]   = sigmoid(qa_embed_w[r] @ erase_W + erase_b)
// eatab[r][256..511] = tanh   (qa_embed_w[r] @ add_W   + add_b)
// ---------------------------------------------------------------------------
__global__ __launch_bounds__(512) void eatab_kernel(
    const float* __restrict__ qa_embed_w,
    const float* __restrict__ erase_W,
    const float* __restrict__ erase_b,
    const float* __restrict__ add_W,
    const float* __restrict__ add_b,
    float*       __restrict__ eatab)
{
    __shared__ float4 qa4[16][32];

    const int tid = threadIdx.x;
    const int r0  = blockIdx.x * 16;

    {
        int row = tid >> 5, k4 = tid & 31;
        int r   = r0 + row; if (r > NQA_) r = NQA_;
        qa4[row][k4] = *reinterpret_cast<const float4*>(
            &qa_embed_w[(size_t)r * QD_ + k4 * 4]);
    }
    __syncthreads();

    const int  c   = tid & 255;
    const bool isE = tid < 256;
    const float* Wp = isE ? erase_W : add_W;

    float acc[16];
    #pragma unroll
    for (int r = 0; r < 16; ++r) acc[r] = 0.f;

    for (int k4 = 0; k4 < 32; ++k4) {
        float w0 = Wp[(size_t)(k4 * 4 + 0) * 256 + c];
        float w1 = Wp[(size_t)(k4 * 4 + 1) * 256 + c];
        float w2 = Wp[(size_t)(k4 * 4 + 2) * 256 + c];
        float w3 = Wp[(size_t)(k4 * 4 + 3) * 256 + c];
        #pragma unroll
        for (int r = 0; r < 16; ++r) {
            float4 qv = qa4[r][k4];
            acc[r] = fmaf(qv.x, w0, acc[r]);
            acc[r] = fmaf(qv.y, w1, acc[r]);
            acc[r] = fmaf(qv.z, w2, acc[r]);
            acc[r] = fmaf(qv.w, w3, acc[r]);
        }
    }

    const float bias = isE ? erase_b[c] : add_b[c];
    #pragma unroll
    for (int r = 0; r < 16; ++r) {
        float x = acc[r] + bias;
        float y;
        if (isE) {
            y = 1.f / (1.f + __expf(-x));
        } else {
            float t  = __expf(-2.f * fabsf(x));
            float ta = (1.f - t) / (1.f + t);
            y = (x < 0.f) ? -ta : ta;
        }
        if (r0 + r < EAROWS)
            eatab[(size_t)(r0 + r) * 512 + tid] = y;
    }
}

// ---------------------------------------------------------------------------
// Scan: 256 blocks (1/batch) x 256 threads (4 waves). Thread tid owns the
// FULL Mv column col=tid: mv[64] in VGPRs. No barriers in the main loop.
// Pipelining (all register lookahead, 2-step unrolled loop, parity A/B):
//  - w(t+1) -> other w VGPR set (16x global_load_dwordx4, same-address
//    broadcast, one 64B fetch/wave), issued at step start, used next step.
//  - e/a(t+2) -> same-parity slot right after consumption (2-step distance).
//  - q/qa index chains from LDS with 3-4 step lead (broadcast ds_read_b32).
// ---------------------------------------------------------------------------
__global__ __launch_bounds__(256, 1) void scan_kernel(
    const int*   __restrict__ q_data,
    const int*   __restrict__ qa_data,
    const float* __restrict__ init_mv,
    const float* __restrict__ wtab,
    const float* __restrict__ eatab,
    float*       __restrict__ out)
{
    __shared__ int qrow[S_];
    __shared__ int qarow[S_];

    const int b   = blockIdx.x;
    const int tid = threadIdx.x;

    for (int i = tid; i < S_; i += 256) {
        qrow[i]  = q_data[b * S_ + i];
        qarow[i] = qa_data[b * S_ + i];
    }
    __syncthreads();

    // full column state
    float mv[64];
    #pragma unroll
    for (int m = 0; m < 64; ++m) mv[m] = init_mv[m * VD_ + tid];
    out[(size_t)b * S_ * VD_ + tid] = 0.f;

    // q chains: qc=q[t], qn=q[t+1] (w addr), qnn=q[t+2]; qa2=qa[t+2] (ea addr)
    int qc  = qrow[0];
    int qn  = qrow[1];
    int qnn = qrow[2];
    int qa2 = qarow[2];
    int qa3 = qarow[3];

    // prime: w(q[0]) -> wA ; ea(qa[0]) -> A slot ; ea(qa[1]) -> B slot
    float4 wA[16], wB[16];
    {
        const float4* wrp = (const float4*)(wtab + (size_t)qrow[0] * 64);
        #pragma unroll
        for (int k = 0; k < 16; ++k) wA[k] = wrp[k];
    }
    float evA, avA, evB, avB;
    {
        const float* r0p = &eatab[(size_t)qarow[0] * 512 + tid];
        evA = r0p[0]; avA = r0p[256];
        const float* r1p = &eatab[(size_t)qarow[1] * 512 + tid];
        evB = r1p[0]; avB = r1p[256];
    }

    float* outp = &out[((size_t)b * S_ + 1) * VD_ + tid];

    #define SCAN_STEP(WC, WL, EV, AV, scur)                                    \
    {                                                                          \
        /* issue next step's w loads (broadcast row, 64B/wave) */              \
        const float4* wrp = (const float4*)(wtab + (size_t)qn * 64);           \
        _Pragma("unroll")                                                      \
        for (int k = 0; k < 16; ++k) WL[k] = wrp[k];                           \
        const bool  wg = qc >= 1;                                              \
        const float em = wg ? EV : 0.f;                                        \
        const float am = wg ? AV : 0.f;                                        \
        /* reload this parity's ea slot for step scur+2 */                     \
        const float* eap = &eatab[(size_t)qa2 * 512 + tid];                    \
        EV = eap[0];                                                           \
        AV = eap[256];                                                         \
        /* q chains: fetch q[scur+3], qa[scur+4]; rotate */                    \
        int t3 = (scur) + 3; if (t3 >= S_) t3 = S_ - 1;                        \
        int t4 = (scur) + 4; if (t4 >= S_) t4 = S_ - 1;                        \
        const int qnew  = qrow[t3];                                            \
        const int qanew = qarow[t4];                                           \
        qc = qn; qn = qnn; qnn = qnew;                                         \
        qa2 = qa3; qa3 = qanew;                                                \
        float r0 = 0.f, r1 = 0.f, r2 = 0.f, r3 = 0.f;                          \
        _Pragma("unroll")                                                      \
        for (int k = 0; k < 16; ++k) {                                         \
            const float4 w4 = WC[k];                                           \
            const float v0 = mv[4 * k + 0];                                    \
            const float v1 = mv[4 * k + 1];                                    \
            const float v2 = mv[4 * k + 2];                                    \
            const float v3 = mv[4 * k + 3];                                    \
            r0 = fmaf(w4.x, v0, r0);                                           \
            r1 = fmaf(w4.y, v1, r1);                                           \
            r2 = fmaf(w4.z, v2, r2);                                           \
            r3 = fmaf(w4.w, v3, r3);                                           \
            mv[4 * k + 0] = fmaf(w4.x, fmaf(-em, v0, am), v0);                 \
            mv[4 * k + 1] = fmaf(w4.y, fmaf(-em, v1, am), v1);                 \
            mv[4 * k + 2] = fmaf(w4.z, fmaf(-em, v2, am), v2);                 \
            mv[4 * k + 3] = fmaf(w4.w, fmaf(-em, v3, am), v3);                 \
        }                                                                      \
        if ((scur) + 2 <= S_)   /* store out[scur+1] iff scur+1 < S_ */        \
            outp[0] = (r0 + r1) + (r2 + r3);                                   \
        outp += VD_;                                                           \
    }

    for (int t = 0; t < S_; t += 2) {
        SCAN_STEP(wA, wB, evA, avA, t)
        SCAN_STEP(wB, wA, evB, avB, t + 1)
    }
    #undef SCAN_STEP
}

// ---------------------------------------------------------------------------
extern "C" void kernel_launch(void* const* d_in, const int* in_sizes, int n_in,
                              void* d_out, int out_size, void* d_ws, size_t ws_size,
                              hipStream_t stream)
{
    const int*   q_data  = (const int*)  d_in[0];
    const int*   qa_data = (const int*)  d_in[1];
    const float* q_emb   = (const float*)d_in[2];
    const float* qa_emb  = (const float*)d_in[3];
    const float* key_mem = (const float*)d_in[4];
    const float* init_mv = (const float*)d_in[5];
    const float* erase_W = (const float*)d_in[6];
    const float* erase_b = (const float*)d_in[7];
    const float* add_W   = (const float*)d_in[8];
    const float* add_b   = (const float*)d_in[9];
    float* out = (float*)d_out;

    char* ws = (char*)d_ws;
    float4* kTq = (float4*)ws;
    size_t off = (size_t)2048 * sizeof(float4);               // 32 KB
    float* wtab = (float*)(ws + off);
    off += (size_t)WROWS * 64 * sizeof(float);                // 2.56 MB
    off = (off + 255) & ~(size_t)255;
    float* eatab = (float*)(ws + off);
    off += (size_t)EAROWS * 512 * sizeof(float);              // 40.96 MB

    kT_kernel<<<dim3(8), dim3(256), 0, stream>>>(key_mem, kTq);
    wtab_kernel<<<dim3((WROWS + 15) / 16), dim3(256), 0, stream>>>(
        q_emb, kTq, wtab);
    eatab_kernel<<<dim3((EAROWS + 15) / 16), dim3(512), 0, stream>>>(
        qa_emb, erase_W, erase_b, add_W, add_b, eatab);
    scan_kernel<<<dim3(B_), dim3(256), 0, stream>>>(
        q_data, qa_data, init_mv, wtab, eatab, out);
}